// Round 1
// baseline (421.326 us; speedup 1.0000x reference)
//
#include <hip/hip_runtime.h>
#include <math.h>

#define S 4096
#define N_NODES 2048
#define N_CHILD 4096
#define NNZ 32768
#define NNZ_TOTAL (2 * NNZ)
#define TS 256   // samples per block in main kernel
#define TN 16    // nodes per block in main kernel

// ---- CSR build ------------------------------------------------------------

__global__ void hist_kernel(const int* __restrict__ r0, const int* __restrict__ r1,
                            int* __restrict__ counts) {
    int k = blockIdx.x * blockDim.x + threadIdx.x;
    int row = (k < NNZ) ? r0[k] : r1[k - NNZ];
    atomicAdd(&counts[row], 1);
}

// exclusive scan of counts[2048] -> offsets[2049], single block of 256 threads
__global__ void scan_kernel(const int* __restrict__ counts, int* __restrict__ offsets) {
    __shared__ int sums[256];
    int t = threadIdx.x;
    int base = t * 8;
    int local[8];
    int s = 0;
    for (int j = 0; j < 8; ++j) { local[j] = s; s += counts[base + j]; }
    sums[t] = s;
    __syncthreads();
    for (int off = 1; off < 256; off <<= 1) {
        int v = (t >= off) ? sums[t - off] : 0;
        __syncthreads();
        sums[t] += v;
        __syncthreads();
    }
    int prefix = (t == 0) ? 0 : sums[t - 1];
    for (int j = 0; j < 8; ++j) offsets[base + j] = prefix + local[j];
    if (t == 255) offsets[N_NODES] = prefix + s;
}

__global__ void scatter_kernel(const int* __restrict__ r0, const int* __restrict__ c0,
                               const float* __restrict__ d0,
                               const int* __restrict__ r1, const int* __restrict__ c1,
                               const float* __restrict__ d1,
                               const int* __restrict__ offsets, int* __restrict__ cursor,
                               int* __restrict__ ent_col, float* __restrict__ ent_ew) {
    int k = blockIdx.x * blockDim.x + threadIdx.x;
    int row, col;
    float w;
    if (k < NNZ) { row = r0[k]; col = c0[k]; w = d0[k]; }
    else         { int kk = k - NNZ; row = r1[kk]; col = c1[kk] + N_CHILD; w = d1[kk]; }
    int pos = offsets[row] + atomicAdd(&cursor[row], 1);
    ent_col[pos] = col;
    ent_ew[pos] = expf(w);
}

// ---- exp + transpose: ET[(c + m*N_CHILD)*S + s] = exp(ll_m[s*N_CHILD + c]) ----

__global__ void texp_kernel(const float* __restrict__ ll0, const float* __restrict__ ll1,
                            float* __restrict__ ET) {
    __shared__ float tile[32][33];
    const float* ll = blockIdx.z ? ll1 : ll0;
    int c0 = blockIdx.x * 32, s0 = blockIdx.y * 32;
    int tx = threadIdx.x, ty = threadIdx.y;  // (32, 8)
    for (int r = ty; r < 32; r += 8)
        tile[r][tx] = ll[(size_t)(s0 + r) * N_CHILD + c0 + tx];   // coalesced read
    __syncthreads();
    float* dst = ET + (size_t)blockIdx.z * N_CHILD * S;
    for (int r = ty; r < 32; r += 8)
        dst[(size_t)(c0 + r) * S + s0 + tx] = expf(tile[tx][r]);  // coalesced write
}

// ---- main: out[s,i] = log(sum_k ET[col_k, s] * ew_k) - log(sum_k ew_k) ----

__global__ __launch_bounds__(256) void main_kernel(const float* __restrict__ ET,
                                                   const int* __restrict__ ent_col,
                                                   const float* __restrict__ ent_ew,
                                                   const int* __restrict__ offsets,
                                                   float* __restrict__ out) {
    __shared__ float lds[TS * (TN + 1)];   // +1 pad: store stride 17 -> 2-way bank alias (free)
    int t = threadIdx.x;
    int s = blockIdx.y * TS + t;
    int i0 = blockIdx.x * TN;
    for (int j = 0; j < TN; ++j) {
        int i = i0 + j;
        int b = __builtin_amdgcn_readfirstlane(offsets[i]);
        int e = __builtin_amdgcn_readfirstlane(offsets[i + 1]);
        float a = 0.f, z = 0.f;
        for (int k = b; k < e; ++k) {
            int c = ent_col[k];          // uniform
            float w = ent_ew[k];         // uniform
            a = fmaf(ET[(size_t)c * S + s], w, a);  // coalesced gather across lanes
            z += w;
        }
        lds[t * (TN + 1) + j] = logf(a) - logf(z);
    }
    __syncthreads();
    // write out tile (TS samples x TN nodes) with full-line coalescing
    float* orow = out + (size_t)blockIdx.y * TS * N_NODES + i0;
    for (int j = 0; j < TN; ++j) {
        int p = t + TS * j;
        int s_l = p >> 4;            // p / TN
        int i_l = p & (TN - 1);      // p % TN
        orow[(size_t)s_l * N_NODES + i_l] = lds[s_l * (TN + 1) + i_l];
    }
}

// ---- launch ---------------------------------------------------------------

extern "C" void kernel_launch(void* const* d_in, const int* in_sizes, int n_in,
                              void* d_out, int out_size, void* d_ws, size_t ws_size,
                              hipStream_t stream) {
    const float* ll0 = (const float*)d_in[0];
    const float* ll1 = (const float*)d_in[1];
    const float* w0d = (const float*)d_in[2];
    const float* w1d = (const float*)d_in[3];
    const int*   w0r = (const int*)d_in[4];
    const int*   w0c = (const int*)d_in[5];
    const int*   w1r = (const int*)d_in[6];
    const int*   w1c = (const int*)d_in[7];
    float* out = (float*)d_out;

    // workspace layout
    float* ET      = (float*)d_ws;                               // 2*N_CHILD*S floats = 128 MiB
    int*   ent_col = (int*)(ET + (size_t)2 * N_CHILD * S);       // 65536 ints
    float* ent_ew  = (float*)(ent_col + NNZ_TOTAL);              // 65536 floats
    int*   counts  = (int*)(ent_ew + NNZ_TOTAL);                 // 2048
    int*   offsets = counts + N_NODES;                           // 2049
    int*   cursor  = offsets + N_NODES + 1;                      // 2048

    hipMemsetAsync(counts, 0, sizeof(int) * (N_NODES + (N_NODES + 1) + N_NODES), stream);
    hist_kernel<<<NNZ_TOTAL / 256, 256, 0, stream>>>(w0r, w1r, counts);
    scan_kernel<<<1, 256, 0, stream>>>(counts, offsets);
    scatter_kernel<<<NNZ_TOTAL / 256, 256, 0, stream>>>(w0r, w0c, w0d, w1r, w1c, w1d,
                                                        offsets, cursor, ent_col, ent_ew);
    dim3 tb(32, 8);
    dim3 tg(N_CHILD / 32, S / 32, 2);
    texp_kernel<<<tg, tb, 0, stream>>>(ll0, ll1, ET);
    dim3 mg(N_NODES / TN, S / TS);
    main_kernel<<<mg, 256, 0, stream>>>(ET, ent_col, ent_ew, offsets, out);
}

// Round 2
// 291.628 us; speedup vs baseline: 1.4447x; 1.4447x over previous
//
#include <hip/hip_runtime.h>
#include <math.h>

#define S 4096
#define N_NODES 2048
#define N_CHILD 4096
#define NNZ 32768
#define NNZ_TOTAL (2 * NNZ)
#define TSM 512   // samples per block in main kernel (64 lanes x 8 bf16)
#define TN 16     // nodes per block in main kernel

typedef unsigned short ushort8v __attribute__((ext_vector_type(8)));

static __device__ inline unsigned short f2bf(float f) {
    unsigned int u = __float_as_uint(f);
    unsigned int r = (u + 0x7FFF + ((u >> 16) & 1)) >> 16;  // round-to-nearest-even
    return (unsigned short)r;
}

// ---- CSR build ------------------------------------------------------------

__global__ void hist_kernel(const int* __restrict__ r0, const int* __restrict__ r1,
                            int* __restrict__ counts) {
    int k = blockIdx.x * blockDim.x + threadIdx.x;
    int row = (k < NNZ) ? r0[k] : r1[k - NNZ];
    atomicAdd(&counts[row], 1);
}

__global__ void scan_kernel(const int* __restrict__ counts, int* __restrict__ offsets) {
    __shared__ int sums[256];
    int t = threadIdx.x;
    int base = t * 8;
    int local[8];
    int s = 0;
    for (int j = 0; j < 8; ++j) { local[j] = s; s += counts[base + j]; }
    sums[t] = s;
    __syncthreads();
    for (int off = 1; off < 256; off <<= 1) {
        int v = (t >= off) ? sums[t - off] : 0;
        __syncthreads();
        sums[t] += v;
        __syncthreads();
    }
    int prefix = (t == 0) ? 0 : sums[t - 1];
    for (int j = 0; j < 8; ++j) offsets[base + j] = prefix + local[j];
    if (t == 255) offsets[N_NODES] = prefix + s;
}

__global__ void scatter_kernel(const int* __restrict__ r0, const int* __restrict__ c0,
                               const float* __restrict__ d0,
                               const int* __restrict__ r1, const int* __restrict__ c1,
                               const float* __restrict__ d1,
                               const int* __restrict__ offsets, int* __restrict__ cursor,
                               int* __restrict__ ent_col, float* __restrict__ ent_ew) {
    int k = blockIdx.x * blockDim.x + threadIdx.x;
    int row, col;
    float w;
    if (k < NNZ) { row = r0[k]; col = c0[k]; w = d0[k]; }
    else         { int kk = k - NNZ; row = r1[kk]; col = c1[kk] + N_CHILD; w = d1[kk]; }
    int pos = offsets[row] + atomicAdd(&cursor[row], 1);
    ent_col[pos] = col;
    ent_ew[pos] = expf(w);
}

// ---- exp + transpose to bf16: ET[(c + m*N_CHILD)*S + s] = bf16(exp(ll_m[s,c])) ----
// tile [col][sample] padded to 129 so both phases are ~conflict-free.

__global__ __launch_bounds__(256) void texp_kernel(const float* __restrict__ ll0,
                                                   const float* __restrict__ ll1,
                                                   unsigned short* __restrict__ ET) {
    __shared__ float tile[32][129];   // 16.5 KB
    const float* ll = blockIdx.z ? ll1 : ll0;
    int c0 = blockIdx.x * 32, s0 = blockIdx.y * 128;
    int t = threadIdx.x;
    int tx = t & 31;        // col
    int ty = t >> 5;        // 0..7
    for (int r = ty; r < 128; r += 8)
        tile[tx][r] = ll[(size_t)(s0 + r) * N_CHILD + c0 + tx];   // coalesced read
    __syncthreads();
    int wave = t >> 6, lane = t & 63;
    unsigned short* dst = ET + (size_t)blockIdx.z * N_CHILD * S;
    for (int p = 0; p < 8; ++p) {
        int c = p * 4 + wave;
        float f0 = __expf(tile[c][2 * lane]);
        float f1 = __expf(tile[c][2 * lane + 1]);
        unsigned int packed = (unsigned int)f2bf(f0) | ((unsigned int)f2bf(f1) << 16);
        // 64 lanes x 4 B = 256 B contiguous per wave store
        *(unsigned int*)(dst + (size_t)(c0 + c) * S + s0 + 2 * lane) = packed;
    }
}

// ---- main: out[s,i] = log(sum_k ET[col_k, s] * ew_k) - log(sum_k ew_k) ----

__global__ __launch_bounds__(256) void main_kernel(const unsigned short* __restrict__ ET,
                                                   const int* __restrict__ ent_col,
                                                   const float* __restrict__ ent_ew,
                                                   const int* __restrict__ offsets,
                                                   float* __restrict__ out) {
    __shared__ float lds[TSM * 17];   // [sample][node], node dim padded 16->17
    int t = threadIdx.x, wave = t >> 6, lane = t & 63;
    const unsigned short* ETs = ET + (size_t)blockIdx.y * TSM + lane * 8;
    int i0 = blockIdx.x * TN;
    for (int jj = 0; jj < 4; ++jj) {
        int j = (wave << 2) + jj;             // each wave owns 4 nodes
        int i = i0 + j;
        int b = __builtin_amdgcn_readfirstlane(offsets[i]);
        int e = __builtin_amdgcn_readfirstlane(offsets[i + 1]);
        float a[8];
#pragma unroll
        for (int u = 0; u < 8; ++u) a[u] = 0.f;
        float z = 0.f;
        int k = b;
        for (; k + 1 < e; k += 2) {
            int c0 = __builtin_amdgcn_readfirstlane(ent_col[k]);
            int c1 = __builtin_amdgcn_readfirstlane(ent_col[k + 1]);
            float w0 = ent_ew[k];
            float w1 = ent_ew[k + 1];
            ushort8v x = *(const ushort8v*)(ETs + (size_t)c0 * S);   // 16 B/lane
            ushort8v y = *(const ushort8v*)(ETs + (size_t)c1 * S);
#pragma unroll
            for (int u = 0; u < 8; ++u)
                a[u] = fmaf(__uint_as_float(((unsigned int)x[u]) << 16), w0, a[u]);
#pragma unroll
            for (int u = 0; u < 8; ++u)
                a[u] = fmaf(__uint_as_float(((unsigned int)y[u]) << 16), w1, a[u]);
            z += w0 + w1;
        }
        if (k < e) {
            int c0 = __builtin_amdgcn_readfirstlane(ent_col[k]);
            float w0 = ent_ew[k];
            ushort8v x = *(const ushort8v*)(ETs + (size_t)c0 * S);
#pragma unroll
            for (int u = 0; u < 8; ++u)
                a[u] = fmaf(__uint_as_float(((unsigned int)x[u]) << 16), w0, a[u]);
            z += w0;
        }
        float lz = __logf(z);
#pragma unroll
        for (int u = 0; u < 8; ++u)
            lds[(lane * 8 + u) * 17 + j] = __logf(a[u]) - lz;
    }
    __syncthreads();
    // write out tile (TSM samples x TN nodes), coalesced 64 B segments
    float* orow = out + (size_t)blockIdx.y * TSM * N_NODES + i0;
#pragma unroll
    for (int q = 0; q < 32; ++q) {
        int p = t + 256 * q;
        int s_l = p >> 4;
        int i_l = p & (TN - 1);
        orow[(size_t)s_l * N_NODES + i_l] = lds[s_l * 17 + i_l];
    }
}

// ---- launch ---------------------------------------------------------------

extern "C" void kernel_launch(void* const* d_in, const int* in_sizes, int n_in,
                              void* d_out, int out_size, void* d_ws, size_t ws_size,
                              hipStream_t stream) {
    const float* ll0 = (const float*)d_in[0];
    const float* ll1 = (const float*)d_in[1];
    const float* w0d = (const float*)d_in[2];
    const float* w1d = (const float*)d_in[3];
    const int*   w0r = (const int*)d_in[4];
    const int*   w0c = (const int*)d_in[5];
    const int*   w1r = (const int*)d_in[6];
    const int*   w1c = (const int*)d_in[7];
    float* out = (float*)d_out;

    // workspace layout
    unsigned short* ET = (unsigned short*)d_ws;                  // 2*N_CHILD*S bf16 = 64 MiB
    int*   ent_col = (int*)(ET + (size_t)2 * N_CHILD * S);       // 65536 ints
    float* ent_ew  = (float*)(ent_col + NNZ_TOTAL);              // 65536 floats
    int*   counts  = (int*)(ent_ew + NNZ_TOTAL);                 // 2048
    int*   offsets = counts + N_NODES;                           // 2049
    int*   cursor  = offsets + N_NODES + 1;                      // 2048

    hipMemsetAsync(counts, 0, sizeof(int) * (N_NODES + (N_NODES + 1) + N_NODES), stream);
    hist_kernel<<<NNZ_TOTAL / 256, 256, 0, stream>>>(w0r, w1r, counts);
    scan_kernel<<<1, 256, 0, stream>>>(counts, offsets);
    scatter_kernel<<<NNZ_TOTAL / 256, 256, 0, stream>>>(w0r, w0c, w0d, w1r, w1c, w1d,
                                                        offsets, cursor, ent_col, ent_ew);
    dim3 tg(N_CHILD / 32, S / 128, 2);
    texp_kernel<<<tg, 256, 0, stream>>>(ll0, ll1, ET);
    dim3 mg(N_NODES / TN, S / TSM);
    main_kernel<<<mg, 256, 0, stream>>>(ET, ent_col, ent_ew, offsets, out);
}